// Round 9
// baseline (622.159 us; speedup 1.0000x reference)
//
#include <hip/hip_runtime.h>
#include <math.h>

#define Bb 8
#define Nn 1024
#define Kk 32
#define Dd 256
#define Hh 8
#define DHh 32
#define TDIMt 16
#define NBnb 32
#define HIDh 128
#define NSns 128
#define SHDs 9
#define EINe 304   // NB + TDIM + 2*NS
#define NCOLS 1536 // vproj 256 | hsrc 128 | hdst 128 | qw 1024

typedef __bf16 bf16_t;
typedef bf16_t bf16x8 __attribute__((ext_vector_type(8)));
typedef bf16_t bf16x4 __attribute__((ext_vector_type(4)));
typedef float floatx4 __attribute__((ext_vector_type(4)));

__device__ __forceinline__ float gelu_fast(float x){
  float g = 1.5957691216057308f*(x + 0.044715f*x*x*x);
  return x*__builtin_amdgcn_rcpf(1.0f + __expf(-g));
}
__device__ __forceinline__ float tanh_fast(float x){
  return 1.0f - 2.0f*__builtin_amdgcn_rcpf(1.0f + __expf(2.0f*x));
}

// ---------------- kNN: one wave per (b,n) ----------------
__global__ __launch_bounds__(64) void knn_kernel(const float* __restrict__ x, int* __restrict__ src){
  int bn = blockIdx.x;
  int b = bn >> 10;
  int n = bn & (Nn-1);
  int lane = threadIdx.x;
  const float* xb = x + (size_t)b*Nn*3;
  float px = xb[n*3+0], py = xb[n*3+1], pz = xb[n*3+2];
  float d2v[16];
  #pragma unroll
  for (int i=0;i<16;i++){
    int j = i*64 + lane;
    float dx = px - xb[j*3+0];
    float dy = py - xb[j*3+1];
    float dz = pz - xb[j*3+2];
    d2v[i] = dx*dx + dy*dy + dz*dz;
  }
  for (int s=0;s<Kk;s++){
    float best = 3.0e38f; int bslot = 0;
    #pragma unroll
    for (int i=0;i<16;i++){
      if (d2v[i] < best){ best = d2v[i]; bslot = i; }
    }
    int bj = bslot*64 + lane;
    #pragma unroll
    for (int off=32; off>=1; off>>=1){
      float ov = __shfl_xor(best, off);
      int   oj = __shfl_xor(bj,   off);
      if (ov < best || (ov == best && oj < bj)){ best = ov; bj = oj; }
    }
    if ((bj & 63) == lane){
      int sl = bj >> 6;
      #pragma unroll
      for (int i=0;i<16;i++) if (i==sl) d2v[i] = 3.0e38f;
    }
    if (lane == 0) src[(size_t)bn*Kk + s] = bj;
  }
}

// ---------------- embed ----------------
__global__ __launch_bounds__(256) void embed_kernel(const float* __restrict__ y, const float* __restrict__ t,
    const float* __restrict__ We, float* __restrict__ node, bf16_t* __restrict__ node_bf){
  int bn = blockIdx.x; int b = bn >> 10;
  int c = threadIdx.x;
  float f0 = y[(size_t)bn*3+0], f1 = y[(size_t)bn*3+1], f2 = y[(size_t)bn*3+2];
  float a = f0*We[0*Dd+c] + f1*We[1*Dd+c] + f2*We[2*Dd+c];
  #pragma unroll
  for (int i=0;i<TDIMt;i++) a += t[b*TDIMt+i]*We[(3+i)*Dd+c];
  node[(size_t)bn*Dd + c] = a;
  node_bf[(size_t)bn*Dd + c] = (bf16_t)a;
}

// ---------------- weight prep: Wt[l][col][k] bf16, cols 0..511 ----------------
__global__ __launch_bounds__(256) void wprep_kernel(const float* __restrict__ Wv,
    const float* __restrict__ Wk1, bf16_t* __restrict__ Wt){
  int l = blockIdx.x, c = blockIdx.y, k = threadIdx.x;
  const float* wk1l = Wk1 + (size_t)l*EINe*HIDh;
  float v;
  if (c < 256)       v = Wv[(size_t)l*265*Dd + (size_t)k*Dd + c];
  else if (c < 384){ int c2 = c-256; v = (k < 128) ? wk1l[(48+k)*HIDh + c2] : 0.0f; }
  else             { int c2 = c-384; v = (k < 128) ? wk1l[(176+k)*HIDh + c2] : 0.0f; }
  Wt[((size_t)l*NCOLS + c)*Dd + k] = (bf16_t)v;
}

// ---------------- weight prep: fused qw weights M[i][h*128+c] -> cols 512..1535 ----------------
__global__ __launch_bounds__(256) void wprepM_kernel(const float* __restrict__ Wq,
    const float* __restrict__ Wk2, bf16_t* __restrict__ Wt){
  int l = blockIdx.x, y = blockIdx.y, i = threadIdx.x;
  int h = y >> 7, c = y & 127;
  const float* wq  = Wq  + (size_t)l*Dd*Dd   + (size_t)i*Dd + h*DHh;
  const float* wk2 = Wk2 + (size_t)l*HIDh*Dd + (size_t)c*Dd + h*DHh;
  float a = 0.0f;
  #pragma unroll
  for (int d=0; d<DHh; d++) a += wq[d]*wk2[d];
  Wt[((size_t)l*NCOLS + 512 + y)*Dd + i] = (bf16_t)a;
}

// ---------------- weight prep: Wo transposed bf16 ----------------
__global__ __launch_bounds__(256) void wprepO_kernel(const float* __restrict__ Wo, bf16_t* __restrict__ Wto){
  int l = blockIdx.x, c = blockIdx.y, k = threadIdx.x;
  Wto[((size_t)l*Dd + c)*Dd + k] = (bf16_t)Wo[(size_t)l*Dd*Dd + (size_t)k*Dd + c];
}

// ---------------- weight prep: WrbfT[l][c][k] bf16 ----------------
__global__ __launch_bounds__(32) void wprepR_kernel(const float* __restrict__ Wk1, bf16_t* __restrict__ WrbfT){
  int l = blockIdx.x, c = blockIdx.y, k = threadIdx.x;   // k < 32
  WrbfT[((size_t)l*HIDh + c)*NBnb + k] = (bf16_t)Wk1[(size_t)l*EINe*HIDh + (size_t)k*HIDh + c];
}

// ---------------- t_hd[l][b][c] = bk1 + t@Wk1_t ----------------
__global__ __launch_bounds__(128) void tprep_kernel(const float* __restrict__ t,
    const float* __restrict__ Wk1, const float* __restrict__ bk1, float* __restrict__ t_hd){
  int l = blockIdx.x, b = blockIdx.y, c = threadIdx.x;
  const float* wk1l = Wk1 + (size_t)l*EINe*HIDh;
  float a = bk1[l*HIDh + c];
  #pragma unroll
  for (int i=0;i<TDIMt;i++) a += t[b*TDIMt+i]*wk1l[(32+i)*HIDh + c];
  t_hd[(l*Bb + b)*HIDh + c] = a;
}

// ---------------- proj GEMM ----------------
// by 0..3 -> vproj_bf (bf16), 4..5 -> hsrc_bf (bf16), 6..7 -> hdst_f (f32), 8..23 -> qw_bf (bf16)
__global__ __launch_bounds__(256) void gemm_proj(const bf16_t* __restrict__ A,
    const bf16_t* __restrict__ Wt_all, bf16_t* __restrict__ vproj_bf,
    bf16_t* __restrict__ hsrc_bf, float* __restrict__ hdst_f,
    bf16_t* __restrict__ qw_bf, int layer){
  const int tid = threadIdx.x;
  const int wave = tid>>6, lane = tid&63;
  const int row16 = lane&15, quad = lane>>4;
  const int m_base = blockIdx.x*128 + wave*32;
  const int n_base = blockIdx.y*64;
  const bf16_t* Bw = Wt_all + (size_t)layer*NCOLS*Dd;

  floatx4 acc[2][4];
  #pragma unroll
  for (int mi=0;mi<2;mi++)
    #pragma unroll
    for (int ni=0;ni<4;ni++){ floatx4 z = {0.f,0.f,0.f,0.f}; acc[mi][ni] = z; }

  const bf16_t* a0p = A  + (size_t)(m_base + row16)*Dd + quad*8;
  const bf16_t* bp  = Bw + (size_t)(n_base + row16)*Dd + quad*8;
  #pragma unroll
  for (int ks=0; ks<8; ks++){
    bf16x8 a0 = *(const bf16x8*)(a0p + ks*32);
    bf16x8 a1 = *(const bf16x8*)(a0p + 16*Dd + ks*32);
    #pragma unroll
    for (int ni=0;ni<4;ni++){
      bf16x8 b = *(const bf16x8*)(bp + (size_t)ni*16*Dd + ks*32);
      acc[0][ni] = __builtin_amdgcn_mfma_f32_16x16x32_bf16(a0, b, acc[0][ni], 0,0,0);
      acc[1][ni] = __builtin_amdgcn_mfma_f32_16x16x32_bf16(a1, b, acc[1][ni], 0,0,0);
    }
  }

  const int by = blockIdx.y;
  #pragma unroll
  for (int mi=0;mi<2;mi++)
    #pragma unroll
    for (int ni=0;ni<4;ni++){
      int col = n_base + ni*16 + row16;
      #pragma unroll
      for (int r=0;r<4;r++){
        int row = m_base + mi*16 + quad*4 + r;
        float v = acc[mi][ni][r];
        if (by < 4)       vproj_bf[(size_t)row*256 + col]       = (bf16_t)v;
        else if (by < 6)  hsrc_bf[(size_t)row*128 + (col-256)]  = (bf16_t)v;
        else if (by < 8)  hdst_f[(size_t)row*128 + (col-384)]   = v;
        else              qw_bf[(size_t)row*1024 + (col-512)]   = (bf16_t)v;
      }
    }
}

// ---------------- upd GEMM: node = act(node + agg_bf @ Wo) ----------------
__global__ __launch_bounds__(256) void gemm_upd(const bf16_t* __restrict__ A,
    const bf16_t* __restrict__ Wto, float* __restrict__ node, bf16_t* __restrict__ node_bf, int layer){
  const int tid = threadIdx.x;
  const int wave = tid>>6, lane = tid&63;
  const int row16 = lane&15, quad = lane>>4;
  const int m_base = blockIdx.x*128 + wave*32;
  const int n_base = blockIdx.y*64;
  const bf16_t* Bw = Wto + (size_t)layer*Dd*Dd;

  floatx4 acc[2][4];
  #pragma unroll
  for (int mi=0;mi<2;mi++)
    #pragma unroll
    for (int ni=0;ni<4;ni++){ floatx4 z = {0.f,0.f,0.f,0.f}; acc[mi][ni] = z; }

  const bf16_t* a0p = A  + (size_t)(m_base + row16)*Dd + quad*8;
  const bf16_t* bp  = Bw + (size_t)(n_base + row16)*Dd + quad*8;
  #pragma unroll
  for (int ks=0; ks<8; ks++){
    bf16x8 a0 = *(const bf16x8*)(a0p + ks*32);
    bf16x8 a1 = *(const bf16x8*)(a0p + 16*Dd + ks*32);
    #pragma unroll
    for (int ni=0;ni<4;ni++){
      bf16x8 b = *(const bf16x8*)(bp + (size_t)ni*16*Dd + ks*32);
      acc[0][ni] = __builtin_amdgcn_mfma_f32_16x16x32_bf16(a0, b, acc[0][ni], 0,0,0);
      acc[1][ni] = __builtin_amdgcn_mfma_f32_16x16x32_bf16(a1, b, acc[1][ni], 0,0,0);
    }
  }

  #pragma unroll
  for (int mi=0;mi<2;mi++)
    #pragma unroll
    for (int ni=0;ni<4;ni++){
      int col = n_base + ni*16 + row16;
      #pragma unroll
      for (int r=0;r<4;r++){
        int row = m_base + mi*16 + quad*4 + r;
        float v = acc[mi][ni][r] + node[(size_t)row*Dd + col];
        if (col < 64)       v = gelu_fast(v);
        else if (col < 128) v = tanh_fast(v);
        node[(size_t)row*Dd + col] = v;
        node_bf[(size_t)row*Dd + col] = (bf16_t)v;
      }
    }
}

// ---------------- attn: block per node, slim LDS (8 blocks/CU target) ----------------
__global__ __launch_bounds__(256) void attn_kernel(
    const float* __restrict__ x, const int* __restrict__ src,
    const bf16_t* __restrict__ vproj_bf, const bf16_t* __restrict__ hsrc_bf,
    const float* __restrict__ hdst_f, const bf16_t* __restrict__ qw_bf,
    const float* __restrict__ t_hd, const bf16_t* __restrict__ WrbfT,
    const float* __restrict__ Wvg, const float* __restrict__ Woo,
    bf16_t* __restrict__ agg_bf, float* __restrict__ out, int layer){

  // manual LDS layout, total 19824 B:
  // [0..16896)  union: { s_rbf[0..2048) + s_h[2048..10752) }  then  s_v[0..16896)
  // [16896..18176) s_sh   f32 [32][10]
  // [18176..18304) s_cut  f32 [32]
  // [18304..18432) s_srcv int [32]
  // [18432..19456) s_logit f32 [32][8]
  // [19456..19776) s_poolsh f32 [8][10]
  // [19776..19824) s_red  f32 [4][3]
  __shared__ __align__(16) char smem[19824];
  bf16_t* s_rbf   = (bf16_t*)(smem);
  bf16_t* s_h     = (bf16_t*)(smem + 2048);     // [32][136] bf16: hs, then h in place
  bf16_t* s_v     = (bf16_t*)(smem);            // [32][264] bf16 (overlay, live after B4)
  float*  s_sh    = (float*)(smem + 16896);     // [k*10 + sg]
  float*  s_cut   = (float*)(smem + 18176);
  int*    s_srcv  = (int*)  (smem + 18304);
  float*  s_logit = (float*)(smem + 18432);     // [k*8 + h]
  float*  s_poolsh= (float*)(smem + 19456);     // [h*10 + sg]
  float*  s_red   = (float*)(smem + 19776);

  const int tid = threadIdx.x;
  const int bn  = blockIdx.x;
  const int b   = bn >> 10;
  const int wave = tid>>6, lane = tid&63;
  const int row16 = lane&15, quad = lane>>4;

  // P0: geometry; thread = (k = tid>>3, i = tid&7)
  {
    int k = tid>>3, i = tid&7;
    int j = src[(size_t)bn*Kk + k];
    if (i == 0) s_srcv[k] = j;
    float ax = x[(size_t)bn*3+0], ay = x[(size_t)bn*3+1], az = x[(size_t)bn*3+2];
    const float* xj = x + ((size_t)b*Nn + j)*3;
    float dx = ax - xj[0], dy = ay - xj[1], dz = az - xj[2];
    float rr = sqrtf(dx*dx + dy*dy + dz*dz);
    float xx = 10.0f*(1.0f - rr*0.5f);
    float cu = (xx > 0.0f) ? 1.4f*__expf(-__builtin_amdgcn_rcpf(xx)) : 0.0f;
    if (i == 0) s_cut[k] = cu;
    if (i == 1){
      float inv = __builtin_amdgcn_rcpf(fmaxf(rr, 1e-9f));
      float ux = dx*inv, uy = dy*inv, uz = dz*inv;
      s_sh[k*10+0] = 1.0f;
      s_sh[k*10+1] = 1.7320508075688772f*ux;
      s_sh[k*10+2] = 1.7320508075688772f*uy;
      s_sh[k*10+3] = 1.7320508075688772f*uz;
      s_sh[k*10+4] = 3.872983346207417f*ux*uy;
      s_sh[k*10+5] = 3.872983346207417f*uy*uz;
      s_sh[k*10+6] = 1.118033988749895f*(3.0f*uz*uz - 1.0f);
      s_sh[k*10+7] = 3.872983346207417f*ux*uz;
      s_sh[k*10+8] = 1.9364916731037085f*(ux*ux - uy*uy);
    }
    float rs = rr*15.5f;
    float base = (float)(i*4);
    bf16x4 pv;
    #pragma unroll
    for (int c=0;c<4;c++){
      float dd = rs - (base + (float)c);
      pv[c] = (bf16_t)(__expf(-dd*dd)*4.798224586623f*cu);
    }
    *(bf16x4*)(s_rbf + (i>>1)*256 + k*8 + (i&1)*4) = pv;
  }
  __syncthreads();   // B1

  // P1: hs staging loads + h-MFMA, stash hs into s_h
  bf16x8 hsv[2]; int hrow[2], hc8[2];
  #pragma unroll
  for (int rep=0;rep<2;rep++){
    int q = tid + rep*256;
    hrow[rep] = q>>4; hc8[rep] = q&15;
    hsv[rep] = *(const bf16x8*)(hsrc_bf + ((size_t)b*Nn + s_srcv[hrow[rep]])*128 + hc8[rep]*8);
  }
  floatx4 acc[2][2];
  {
    #pragma unroll
    for (int mi=0;mi<2;mi++)
      #pragma unroll
      for (int ni=0;ni<2;ni++){ floatx4 z = {0.f,0.f,0.f,0.f}; acc[mi][ni] = z; }
    bf16x8 a0 = *(const bf16x8*)(s_rbf + quad*256 + row16*8);
    bf16x8 a1 = *(const bf16x8*)(s_rbf + quad*256 + (16+row16)*8);
    const bf16_t* bp = WrbfT + ((size_t)layer*HIDh + wave*32 + row16)*NBnb + quad*8;
    bf16x8 b0 = *(const bf16x8*)(bp);
    bf16x8 b1 = *(const bf16x8*)(bp + 16*NBnb);
    acc[0][0] = __builtin_amdgcn_mfma_f32_16x16x32_bf16(a0, b0, acc[0][0], 0,0,0);
    acc[0][1] = __builtin_amdgcn_mfma_f32_16x16x32_bf16(a0, b1, acc[0][1], 0,0,0);
    acc[1][0] = __builtin_amdgcn_mfma_f32_16x16x32_bf16(a1, b0, acc[1][0], 0,0,0);
    acc[1][1] = __builtin_amdgcn_mfma_f32_16x16x32_bf16(a1, b1, acc[1][1], 0,0,0);
  }
  #pragma unroll
  for (int rep=0;rep<2;rep++)
    *(bf16x8*)(s_h + hrow[rep]*136 + hc8[rep]*8) = hsv[rep];
  __syncthreads();   // B2

  // P2: epilogue — h = gelu(acc + hd + hs), IN PLACE in s_h (each elem R/W by same thread)
  #pragma unroll
  for (int ni=0;ni<2;ni++){
    int c = wave*32 + ni*16 + row16;
    float hdv = hdst_f[(size_t)bn*128 + c] + t_hd[(size_t)(layer*Bb + b)*HIDh + c];
    #pragma unroll
    for (int mi=0;mi<2;mi++){
      #pragma unroll
      for (int r=0;r<4;r++){
        int e = mi*16 + quad*4 + r;
        float hs = (float)s_h[e*136 + c];
        s_h[e*136 + c] = (bf16_t)gelu_fast(acc[mi][ni][r] + hdv + hs);
      }
    }
  }
  __syncthreads();   // B3

  // P3: issue v staging loads (regs), logits MFMA on waves 0,1
  bf16x8 vv[4]; int vrow[4], vc8[4];
  #pragma unroll
  for (int rep=0;rep<4;rep++){
    int q = tid + rep*256;
    vrow[rep] = q>>5; vc8[rep] = q&31;
    vv[rep] = *(const bf16x8*)(vproj_bf + ((size_t)b*Nn + s_srcv[vrow[rep]])*256 + vc8[rep]*8);
  }
  if (wave < 2){
    floatx4 la = {0.f,0.f,0.f,0.f};
    const bf16_t* qp = qw_bf + (size_t)bn*1024 + row16*HIDh + quad*8;
    #pragma unroll
    for (int ks=0; ks<4; ks++){
      bf16x8 a = *(const bf16x8*)(s_h + (wave*16 + row16)*136 + ks*32 + quad*8);
      bf16x8 bq = *(const bf16x8*)(qp + ks*32);
      la = __builtin_amdgcn_mfma_f32_16x16x32_bf16(a, bq, la, 0,0,0);
    }
    if (row16 < Hh){
      #pragma unroll
      for (int r=0;r<4;r++)
        s_logit[(wave*16 + quad*4 + r)*8 + row16] = la[r]*0.17677669529663687f;
    }
  }
  __syncthreads();   // B4 — s_rbf/s_h now dead

  // P4: write v into overlay region
  #pragma unroll
  for (int rep=0;rep<4;rep++)
    *(bf16x8*)(s_v + vrow[rep]*264 + vc8[rep]*8) = vv[rep];
  __syncthreads();   // B5

  // P5: softmax + pooling + SH pooling + store / fused out
  {
    const int l = tid & 63;
    const int k = l & 31;
    const int h = tid >> 5;
    float lv = s_logit[k*8 + h];
    float m = lv;
    #pragma unroll
    for (int off=16; off>=1; off>>=1) m = fmaxf(m, __shfl_xor(m, off));
    float w = s_cut[k]*__expf(lv - m);
    float ss = w;
    #pragma unroll
    for (int off=16; off>=1; off>>=1) ss += __shfl_xor(ss, off);
    float alpha = w*__builtin_amdgcn_rcpf(ss + 1e-9f);

    const int half = l & 32;
    const int sgi = (k < SHDs) ? k : 0;
    float a_main = 0.0f, a_sh = 0.0f;
    #pragma unroll
    for (int kk=0; kk<Kk; kk++){
      float av = __shfl(alpha, half + kk);
      a_main += av * (float)s_v[kk*264 + tid];
      a_sh   += av * s_sh[kk*10 + sgi];
    }
    if (k < SHDs) s_poolsh[h*10 + k] = a_sh;

    // same-wave LDS write->read (DS ops in-order within a wave)
    const float* wvsh = Wvg + (size_t)layer*265*Dd + 256*Dd;
    #pragma unroll
    for (int sg=0; sg<SHDs; sg++) a_main += s_poolsh[h*10 + sg]*wvsh[sg*Dd + tid];

    if (layer < 3){
      agg_bf[(size_t)bn*Dd + tid] = (bf16_t)a_main;
    } else {
      float p0 = a_main*Woo[tid*3+0];
      float p1 = a_main*Woo[tid*3+1];
      float p2 = a_main*Woo[tid*3+2];
      #pragma unroll
      for (int off=32; off>=1; off>>=1){
        p0 += __shfl_xor(p0, off);
        p1 += __shfl_xor(p1, off);
        p2 += __shfl_xor(p2, off);
      }
      if (lane == 0){ s_red[wave*3+0]=p0; s_red[wave*3+1]=p1; s_red[wave*3+2]=p2; }
      __syncthreads();
      if (tid < 3)
        out[(size_t)bn*3 + tid] = s_red[0*3+tid]+s_red[1*3+tid]+s_red[2*3+tid]+s_red[3*3+tid];
    }
  }
}

extern "C" void kernel_launch(void* const* d_in, const int* in_sizes, int n_in,
                              void* d_out, int out_size, void* d_ws, size_t ws_size,
                              hipStream_t stream){
  const float* x   = (const float*)d_in[0];
  const float* y   = (const float*)d_in[1];
  const float* t   = (const float*)d_in[2];
  const float* We  = (const float*)d_in[3];
  const float* Wk1 = (const float*)d_in[4];
  const float* bk1 = (const float*)d_in[5];
  const float* Wk2 = (const float*)d_in[6];
  const float* Wq  = (const float*)d_in[7];
  const float* Wv  = (const float*)d_in[8];
  const float* Wo  = (const float*)d_in[9];
  const float* Woo = (const float*)d_in[10];
  float* out = (float*)d_out;

  char* ws = (char*)d_ws;
  size_t off = 0;
  auto take = [&](size_t bytes)->char*{ char* p = ws + off; off = (off + bytes + 255) & ~(size_t)255; return p; };

  int*    src      = (int*)   take((size_t)Bb*Nn*Kk*4);
  float*  node     = (float*) take((size_t)Bb*Nn*Dd*4);
  bf16_t* node_bf  = (bf16_t*)take((size_t)Bb*Nn*Dd*2);
  bf16_t* agg_bf   = (bf16_t*)take((size_t)Bb*Nn*Dd*2);
  bf16_t* vproj_bf = (bf16_t*)take((size_t)Bb*Nn*256*2);
  bf16_t* hsrc_bf  = (bf16_t*)take((size_t)Bb*Nn*128*2);
  float*  hdst_f   = (float*) take((size_t)Bb*Nn*128*4);
  bf16_t* qw_bf    = (bf16_t*)take(((size_t)Bb*Nn*1024 + 2048)*2);  // +pad for B-frag overread
  bf16_t* Wt       = (bf16_t*)take((size_t)4*NCOLS*Dd*2);
  bf16_t* Wto      = (bf16_t*)take((size_t)3*Dd*Dd*2);
  bf16_t* WrbfT    = (bf16_t*)take((size_t)4*HIDh*NBnb*2);
  float*  t_hd     = (float*) take((size_t)4*Bb*HIDh*4);

  // weight prep
  wprep_kernel <<<dim3(4,512),  256, 0, stream>>>(Wv, Wk1, Wt);
  wprepM_kernel<<<dim3(4,1024), 256, 0, stream>>>(Wq, Wk2, Wt);
  wprepO_kernel<<<dim3(3,256),  256, 0, stream>>>(Wo, Wto);
  wprepR_kernel<<<dim3(4,128),  32,  0, stream>>>(Wk1, WrbfT);
  tprep_kernel <<<dim3(4,8),    128, 0, stream>>>(t, Wk1, bk1, t_hd);

  knn_kernel  <<<dim3(Bb*Nn), 64,  0, stream>>>(x, src);
  embed_kernel<<<dim3(Bb*Nn), 256, 0, stream>>>(y, t, We, node, node_bf);

  for (int l=0; l<4; l++){
    gemm_proj<<<dim3(64,24), 256, 0, stream>>>(node_bf, Wt, vproj_bf, hsrc_bf, hdst_f, qw_bf, l);
    attn_kernel<<<dim3(Bb*Nn), 256, 0, stream>>>(x, src, vproj_bf, hsrc_bf, hdst_f, qw_bf,
                                                 t_hd, WrbfT, Wv, Woo, agg_bf, out, l);
    if (l < 3){
      gemm_upd<<<dim3(64,4), 256, 0, stream>>>(agg_bf, Wto, node, node_bf, l);
    }
  }
}

// Round 10
// 613.665 us; speedup vs baseline: 1.0138x; 1.0138x over previous
//
#include <hip/hip_runtime.h>
#include <math.h>

#define Bb 8
#define Nn 1024
#define Kk 32
#define Dd 256
#define Hh 8
#define DHh 32
#define TDIMt 16
#define NBnb 32
#define HIDh 128
#define NSns 128
#define SHDs 9
#define EINe 304   // NB + TDIM + 2*NS
#define NCOLS 1536 // vproj 256 | hsrc 128 | hdst 128 | qw 1024

typedef __bf16 bf16_t;
typedef bf16_t bf16x8 __attribute__((ext_vector_type(8)));
typedef bf16_t bf16x4 __attribute__((ext_vector_type(4)));
typedef float floatx4 __attribute__((ext_vector_type(4)));

__device__ __forceinline__ float gelu_fast(float x){
  float g = 1.5957691216057308f*(x + 0.044715f*x*x*x);
  return x*__builtin_amdgcn_rcpf(1.0f + __expf(-g));
}
__device__ __forceinline__ float tanh_fast(float x){
  return 1.0f - 2.0f*__builtin_amdgcn_rcpf(1.0f + __expf(2.0f*x));
}

// ---------------- kNN: 256-thread blocks, one wave per node (4 nodes/block) ----------------
__global__ __launch_bounds__(256) void knn_kernel(const float* __restrict__ x, int* __restrict__ src){
  int wave = threadIdx.x >> 6;
  int lane = threadIdx.x & 63;
  int bn = blockIdx.x*4 + wave;
  int b = bn >> 10;
  int n = bn & (Nn-1);
  const float* xb = x + (size_t)b*Nn*3;
  float px = xb[n*3+0], py = xb[n*3+1], pz = xb[n*3+2];
  float d2v[16];
  #pragma unroll
  for (int i=0;i<16;i++){
    int j = i*64 + lane;
    float dx = px - xb[j*3+0];
    float dy = py - xb[j*3+1];
    float dz = pz - xb[j*3+2];
    d2v[i] = dx*dx + dy*dy + dz*dz;
  }
  for (int s=0;s<Kk;s++){
    float best = 3.0e38f; int bslot = 0;
    #pragma unroll
    for (int i=0;i<16;i++){
      if (d2v[i] < best){ best = d2v[i]; bslot = i; }
    }
    int bj = bslot*64 + lane;
    #pragma unroll
    for (int off=32; off>=1; off>>=1){
      float ov = __shfl_xor(best, off);
      int   oj = __shfl_xor(bj,   off);
      if (ov < best || (ov == best && oj < bj)){ best = ov; bj = oj; }
    }
    if ((bj & 63) == lane){
      int sl = bj >> 6;
      #pragma unroll
      for (int i=0;i<16;i++) if (i==sl) d2v[i] = 3.0e38f;
    }
    if (lane == 0) src[(size_t)bn*Kk + s] = bj;
  }
}

// ---------------- embed ----------------
__global__ __launch_bounds__(256) void embed_kernel(const float* __restrict__ y, const float* __restrict__ t,
    const float* __restrict__ We, float* __restrict__ node, bf16_t* __restrict__ node_bf){
  int bn = blockIdx.x; int b = bn >> 10;
  int c = threadIdx.x;
  float f0 = y[(size_t)bn*3+0], f1 = y[(size_t)bn*3+1], f2 = y[(size_t)bn*3+2];
  float a = f0*We[0*Dd+c] + f1*We[1*Dd+c] + f2*We[2*Dd+c];
  #pragma unroll
  for (int i=0;i<TDIMt;i++) a += t[b*TDIMt+i]*We[(3+i)*Dd+c];
  node[(size_t)bn*Dd + c] = a;
  node_bf[(size_t)bn*Dd + c] = (bf16_t)a;
}

// ---------------- weight prep: Wt[l][col][k] bf16, cols 0..511 ----------------
__global__ __launch_bounds__(256) void wprep_kernel(const float* __restrict__ Wv,
    const float* __restrict__ Wk1, bf16_t* __restrict__ Wt){
  int l = blockIdx.x, c = blockIdx.y, k = threadIdx.x;
  const float* wk1l = Wk1 + (size_t)l*EINe*HIDh;
  float v;
  if (c < 256)       v = Wv[(size_t)l*265*Dd + (size_t)k*Dd + c];
  else if (c < 384){ int c2 = c-256; v = (k < 128) ? wk1l[(48+k)*HIDh + c2] : 0.0f; }
  else             { int c2 = c-384; v = (k < 128) ? wk1l[(176+k)*HIDh + c2] : 0.0f; }
  Wt[((size_t)l*NCOLS + c)*Dd + k] = (bf16_t)v;
}

// ---------------- weight prep: fused qw weights M[i][h*128+c] -> cols 512..1535 ----------------
__global__ __launch_bounds__(256) void wprepM_kernel(const float* __restrict__ Wq,
    const float* __restrict__ Wk2, bf16_t* __restrict__ Wt){
  int l = blockIdx.x, y = blockIdx.y, i = threadIdx.x;
  int h = y >> 7, c = y & 127;
  const float* wq  = Wq  + (size_t)l*Dd*Dd   + (size_t)i*Dd + h*DHh;
  const float* wk2 = Wk2 + (size_t)l*HIDh*Dd + (size_t)c*Dd + h*DHh;
  float a = 0.0f;
  #pragma unroll
  for (int d=0; d<DHh; d++) a += wq[d]*wk2[d];
  Wt[((size_t)l*NCOLS + 512 + y)*Dd + i] = (bf16_t)a;
}

// ---------------- weight prep: Wo transposed bf16 ----------------
__global__ __launch_bounds__(256) void wprepO_kernel(const float* __restrict__ Wo, bf16_t* __restrict__ Wto){
  int l = blockIdx.x, c = blockIdx.y, k = threadIdx.x;
  Wto[((size_t)l*Dd + c)*Dd + k] = (bf16_t)Wo[(size_t)l*Dd*Dd + (size_t)k*Dd + c];
}

// ---------------- weight prep: WrbfT[l][c][k] bf16 ----------------
__global__ __launch_bounds__(32) void wprepR_kernel(const float* __restrict__ Wk1, bf16_t* __restrict__ WrbfT){
  int l = blockIdx.x, c = blockIdx.y, k = threadIdx.x;   // k < 32
  WrbfT[((size_t)l*HIDh + c)*NBnb + k] = (bf16_t)Wk1[(size_t)l*EINe*HIDh + (size_t)k*HIDh + c];
}

// ---------------- t_hd[l][b][c] = bk1 + t@Wk1_t ----------------
__global__ __launch_bounds__(128) void tprep_kernel(const float* __restrict__ t,
    const float* __restrict__ Wk1, const float* __restrict__ bk1, float* __restrict__ t_hd){
  int l = blockIdx.x, b = blockIdx.y, c = threadIdx.x;
  const float* wk1l = Wk1 + (size_t)l*EINe*HIDh;
  float a = bk1[l*HIDh + c];
  #pragma unroll
  for (int i=0;i<TDIMt;i++) a += t[b*TDIMt+i]*wk1l[(32+i)*HIDh + c];
  t_hd[(l*Bb + b)*HIDh + c] = a;
}

// ---------------- proj GEMM ----------------
// by 0..3 -> vproj_bf (bf16), 4..5 -> hsrc_bf (bf16), 6..7 -> hdst_f (f32), 8..23 -> qw_bf (bf16)
__global__ __launch_bounds__(256) void gemm_proj(const bf16_t* __restrict__ A,
    const bf16_t* __restrict__ Wt_all, bf16_t* __restrict__ vproj_bf,
    bf16_t* __restrict__ hsrc_bf, float* __restrict__ hdst_f,
    bf16_t* __restrict__ qw_bf, int layer){
  const int tid = threadIdx.x;
  const int wave = tid>>6, lane = tid&63;
  const int row16 = lane&15, quad = lane>>4;
  const int m_base = blockIdx.x*128 + wave*32;
  const int n_base = blockIdx.y*64;
  const bf16_t* Bw = Wt_all + (size_t)layer*NCOLS*Dd;

  floatx4 acc[2][4];
  #pragma unroll
  for (int mi=0;mi<2;mi++)
    #pragma unroll
    for (int ni=0;ni<4;ni++){ floatx4 z = {0.f,0.f,0.f,0.f}; acc[mi][ni] = z; }

  const bf16_t* a0p = A  + (size_t)(m_base + row16)*Dd + quad*8;
  const bf16_t* bp  = Bw + (size_t)(n_base + row16)*Dd + quad*8;
  #pragma unroll
  for (int ks=0; ks<8; ks++){
    bf16x8 a0 = *(const bf16x8*)(a0p + ks*32);
    bf16x8 a1 = *(const bf16x8*)(a0p + 16*Dd + ks*32);
    #pragma unroll
    for (int ni=0;ni<4;ni++){
      bf16x8 b = *(const bf16x8*)(bp + (size_t)ni*16*Dd + ks*32);
      acc[0][ni] = __builtin_amdgcn_mfma_f32_16x16x32_bf16(a0, b, acc[0][ni], 0,0,0);
      acc[1][ni] = __builtin_amdgcn_mfma_f32_16x16x32_bf16(a1, b, acc[1][ni], 0,0,0);
    }
  }

  const int by = blockIdx.y;
  #pragma unroll
  for (int mi=0;mi<2;mi++)
    #pragma unroll
    for (int ni=0;ni<4;ni++){
      int col = n_base + ni*16 + row16;
      #pragma unroll
      for (int r=0;r<4;r++){
        int row = m_base + mi*16 + quad*4 + r;
        float v = acc[mi][ni][r];
        if (by < 4)       vproj_bf[(size_t)row*256 + col]       = (bf16_t)v;
        else if (by < 6)  hsrc_bf[(size_t)row*128 + (col-256)]  = (bf16_t)v;
        else if (by < 8)  hdst_f[(size_t)row*128 + (col-384)]   = v;
        else              qw_bf[(size_t)row*1024 + (col-512)]   = (bf16_t)v;
      }
    }
}

// ---------------- upd GEMM: node = act(node + agg_bf @ Wo) ----------------
__global__ __launch_bounds__(256) void gemm_upd(const bf16_t* __restrict__ A,
    const bf16_t* __restrict__ Wto, float* __restrict__ node, bf16_t* __restrict__ node_bf, int layer){
  const int tid = threadIdx.x;
  const int wave = tid>>6, lane = tid&63;
  const int row16 = lane&15, quad = lane>>4;
  const int m_base = blockIdx.x*128 + wave*32;
  const int n_base = blockIdx.y*64;
  const bf16_t* Bw = Wto + (size_t)layer*Dd*Dd;

  floatx4 acc[2][4];
  #pragma unroll
  for (int mi=0;mi<2;mi++)
    #pragma unroll
    for (int ni=0;ni<4;ni++){ floatx4 z = {0.f,0.f,0.f,0.f}; acc[mi][ni] = z; }

  const bf16_t* a0p = A  + (size_t)(m_base + row16)*Dd + quad*8;
  const bf16_t* bp  = Bw + (size_t)(n_base + row16)*Dd + quad*8;
  #pragma unroll
  for (int ks=0; ks<8; ks++){
    bf16x8 a0 = *(const bf16x8*)(a0p + ks*32);
    bf16x8 a1 = *(const bf16x8*)(a0p + 16*Dd + ks*32);
    #pragma unroll
    for (int ni=0;ni<4;ni++){
      bf16x8 b = *(const bf16x8*)(bp + (size_t)ni*16*Dd + ks*32);
      acc[0][ni] = __builtin_amdgcn_mfma_f32_16x16x32_bf16(a0, b, acc[0][ni], 0,0,0);
      acc[1][ni] = __builtin_amdgcn_mfma_f32_16x16x32_bf16(a1, b, acc[1][ni], 0,0,0);
    }
  }

  #pragma unroll
  for (int mi=0;mi<2;mi++)
    #pragma unroll
    for (int ni=0;ni<4;ni++){
      int col = n_base + ni*16 + row16;
      #pragma unroll
      for (int r=0;r<4;r++){
        int row = m_base + mi*16 + quad*4 + r;
        float v = acc[mi][ni][r] + node[(size_t)row*Dd + col];
        if (col < 64)       v = gelu_fast(v);
        else if (col < 128) v = tanh_fast(v);
        node[(size_t)row*Dd + col] = v;
        node_bf[(size_t)row*Dd + col] = (bf16_t)v;
      }
    }
}

// ---------------- attn: block per node, direct coalesced v gathers ----------------
__global__ __launch_bounds__(256) void attn_kernel(
    const float* __restrict__ x, const int* __restrict__ src,
    const bf16_t* __restrict__ vproj_bf, const bf16_t* __restrict__ hsrc_bf,
    const float* __restrict__ hdst_f, const bf16_t* __restrict__ qw_bf,
    const float* __restrict__ t_hd, const bf16_t* __restrict__ WrbfT,
    const float* __restrict__ Wvg, const float* __restrict__ Woo,
    bf16_t* __restrict__ agg_bf, float* __restrict__ out, int layer){

  // manual LDS layout, total 13680 B:
  // [0..2048)      s_rbf bf16 (A-fragment order)
  // [2048..10752)  s_h   bf16 [32][136]  (hs, then h in place)
  // [10752..12032) s_sh  f32 [32][10]
  // [12032..12160) s_cut f32 [32]
  // [12160..12288) s_srcv int [32]
  // [12288..13312) s_logit f32 [32][8]
  // [13312..13632) s_poolsh f32 [8][10]
  // [13632..13680) s_red f32 [4][3]
  __shared__ __align__(16) char smem[13680];
  bf16_t* s_rbf   = (bf16_t*)(smem);
  bf16_t* s_h     = (bf16_t*)(smem + 2048);
  float*  s_sh    = (float*)(smem + 10752);
  float*  s_cut   = (float*)(smem + 12032);
  int*    s_srcv  = (int*)  (smem + 12160);
  float*  s_logit = (float*)(smem + 12288);
  float*  s_poolsh= (float*)(smem + 13312);
  float*  s_red   = (float*)(smem + 13632);

  const int tid = threadIdx.x;
  const int bn  = blockIdx.x;
  const int b   = bn >> 10;
  const int wave = tid>>6, lane = tid&63;
  const int row16 = lane&15, quad = lane>>4;

  // P0: geometry; thread = (k = tid>>3, i = tid&7)
  {
    int k = tid>>3, i = tid&7;
    int j = src[(size_t)bn*Kk + k];
    if (i == 0) s_srcv[k] = j;
    float ax = x[(size_t)bn*3+0], ay = x[(size_t)bn*3+1], az = x[(size_t)bn*3+2];
    const float* xj = x + ((size_t)b*Nn + j)*3;
    float dx = ax - xj[0], dy = ay - xj[1], dz = az - xj[2];
    float rr = sqrtf(dx*dx + dy*dy + dz*dz);
    float xx = 10.0f*(1.0f - rr*0.5f);
    float cu = (xx > 0.0f) ? 1.4f*__expf(-__builtin_amdgcn_rcpf(xx)) : 0.0f;
    if (i == 0) s_cut[k] = cu;
    if (i == 1){
      float inv = __builtin_amdgcn_rcpf(fmaxf(rr, 1e-9f));
      float ux = dx*inv, uy = dy*inv, uz = dz*inv;
      s_sh[k*10+0] = 1.0f;
      s_sh[k*10+1] = 1.7320508075688772f*ux;
      s_sh[k*10+2] = 1.7320508075688772f*uy;
      s_sh[k*10+3] = 1.7320508075688772f*uz;
      s_sh[k*10+4] = 3.872983346207417f*ux*uy;
      s_sh[k*10+5] = 3.872983346207417f*uy*uz;
      s_sh[k*10+6] = 1.118033988749895f*(3.0f*uz*uz - 1.0f);
      s_sh[k*10+7] = 3.872983346207417f*ux*uz;
      s_sh[k*10+8] = 1.9364916731037085f*(ux*ux - uy*uy);
    }
    float rs = rr*15.5f;
    float base = (float)(i*4);
    bf16x4 pv;
    #pragma unroll
    for (int c=0;c<4;c++){
      float dd = rs - (base + (float)c);
      pv[c] = (bf16_t)(__expf(-dd*dd)*4.798224586623f*cu);
    }
    *(bf16x4*)(s_rbf + (i>>1)*256 + k*8 + (i&1)*4) = pv;
  }
  __syncthreads();   // B1

  // P1: hs staging loads + h-MFMA, stash hs into s_h
  bf16x8 hsv[2]; int hrow[2], hc8[2];
  #pragma unroll
  for (int rep=0;rep<2;rep++){
    int q = tid + rep*256;
    hrow[rep] = q>>4; hc8[rep] = q&15;
    hsv[rep] = *(const bf16x8*)(hsrc_bf + ((size_t)b*Nn + s_srcv[hrow[rep]])*128 + hc8[rep]*8);
  }
  floatx4 acc[2][2];
  {
    #pragma unroll
    for (int mi=0;mi<2;mi++)
      #pragma unroll
      for (int ni=0;ni<2;ni++){ floatx4 z = {0.f,0.f,0.f,0.f}; acc[mi][ni] = z; }
    bf16x8 a0 = *(const bf16x8*)(s_rbf + quad*256 + row16*8);
    bf16x8 a1 = *(const bf16x8*)(s_rbf + quad*256 + (16+row16)*8);
    const bf16_t* bp = WrbfT + ((size_t)layer*HIDh + wave*32 + row16)*NBnb + quad*8;
    bf16x8 b0 = *(const bf16x8*)(bp);
    bf16x8 b1 = *(const bf16x8*)(bp + 16*NBnb);
    acc[0][0] = __builtin_amdgcn_mfma_f32_16x16x32_bf16(a0, b0, acc[0][0], 0,0,0);
    acc[0][1] = __builtin_amdgcn_mfma_f32_16x16x32_bf16(a0, b1, acc[0][1], 0,0,0);
    acc[1][0] = __builtin_amdgcn_mfma_f32_16x16x32_bf16(a1, b0, acc[1][0], 0,0,0);
    acc[1][1] = __builtin_amdgcn_mfma_f32_16x16x32_bf16(a1, b1, acc[1][1], 0,0,0);
  }
  #pragma unroll
  for (int rep=0;rep<2;rep++)
    *(bf16x8*)(s_h + hrow[rep]*136 + hc8[rep]*8) = hsv[rep];
  __syncthreads();   // B2

  // P2: epilogue — h = gelu(acc + hd + hs), IN PLACE in s_h
  #pragma unroll
  for (int ni=0;ni<2;ni++){
    int c = wave*32 + ni*16 + row16;
    float hdv = hdst_f[(size_t)bn*128 + c] + t_hd[(size_t)(layer*Bb + b)*HIDh + c];
    #pragma unroll
    for (int mi=0;mi<2;mi++){
      #pragma unroll
      for (int r=0;r<4;r++){
        int e = mi*16 + quad*4 + r;
        float hs = (float)s_h[e*136 + c];
        s_h[e*136 + c] = (bf16_t)gelu_fast(acc[mi][ni][r] + hdv + hs);
      }
    }
  }
  __syncthreads();   // B3

  // P3: logits MFMA on waves 0,1
  if (wave < 2){
    floatx4 la = {0.f,0.f,0.f,0.f};
    const bf16_t* qp = qw_bf + (size_t)bn*1024 + row16*HIDh + quad*8;
    #pragma unroll
    for (int ks=0; ks<4; ks++){
      bf16x8 a = *(const bf16x8*)(s_h + (wave*16 + row16)*136 + ks*32 + quad*8);
      bf16x8 bq = *(const bf16x8*)(qp + ks*32);
      la = __builtin_amdgcn_mfma_f32_16x16x32_bf16(a, bq, la, 0,0,0);
    }
    if (row16 < Hh){
      #pragma unroll
      for (int r=0;r<4;r++)
        s_logit[(wave*16 + quad*4 + r)*8 + row16] = la[r]*0.17677669529663687f;
    }
  }
  __syncthreads();   // B4

  // P4: softmax + pooling (direct coalesced global gathers) + SH pooling + store / fused out
  {
    const int l = tid & 63;
    const int k = l & 31;
    const int h = tid >> 5;
    float lv = s_logit[k*8 + h];
    float m = lv;
    #pragma unroll
    for (int off=16; off>=1; off>>=1) m = fmaxf(m, __shfl_xor(m, off));
    float w = s_cut[k]*__expf(lv - m);
    float ss = w;
    #pragma unroll
    for (int off=16; off>=1; off>>=1) ss += __shfl_xor(ss, off);
    float alpha = w*__builtin_amdgcn_rcpf(ss + 1e-9f);

    const int half = l & 32;
    const int sgi = (k < SHDs) ? k : 0;
    float a_main = 0.0f, a_sh = 0.0f;
    #pragma unroll
    for (int kk=0; kk<Kk; kk++){
      float av = __shfl(alpha, half + kk);
      a_main += av * (float)vproj_bf[((size_t)b*Nn + s_srcv[kk])*256 + tid];
      a_sh   += av * s_sh[kk*10 + sgi];
    }
    if (k < SHDs) s_poolsh[h*10 + k] = a_sh;

    // same-wave LDS write->read (DS ops in-order within a wave)
    const float* wvsh = Wvg + (size_t)layer*265*Dd + 256*Dd;
    #pragma unroll
    for (int sg=0; sg<SHDs; sg++) a_main += s_poolsh[h*10 + sg]*wvsh[sg*Dd + tid];

    if (layer < 3){
      agg_bf[(size_t)bn*Dd + tid] = (bf16_t)a_main;
    } else {
      float p0 = a_main*Woo[tid*3+0];
      float p1 = a_main*Woo[tid*3+1];
      float p2 = a_main*Woo[tid*3+2];
      #pragma unroll
      for (int off=32; off>=1; off>>=1){
        p0 += __shfl_xor(p0, off);
        p1 += __shfl_xor(p1, off);
        p2 += __shfl_xor(p2, off);
      }
      if (lane == 0){ s_red[wave*3+0]=p0; s_red[wave*3+1]=p1; s_red[wave*3+2]=p2; }
      __syncthreads();
      if (tid < 3)
        out[(size_t)bn*3 + tid] = s_red[0*3+tid]+s_red[1*3+tid]+s_red[2*3+tid]+s_red[3*3+tid];
    }
  }
}

extern "C" void kernel_launch(void* const* d_in, const int* in_sizes, int n_in,
                              void* d_out, int out_size, void* d_ws, size_t ws_size,
                              hipStream_t stream){
  const float* x   = (const float*)d_in[0];
  const float* y   = (const float*)d_in[1];
  const float* t   = (const float*)d_in[2];
  const float* We  = (const float*)d_in[3];
  const float* Wk1 = (const float*)d_in[4];
  const float* bk1 = (const float*)d_in[5];
  const float* Wk2 = (const float*)d_in[6];
  const float* Wq  = (const float*)d_in[7];
  const float* Wv  = (const float*)d_in[8];
  const float* Wo  = (const float*)d_in[9];
  const float* Woo = (const float*)d_in[10];
  float* out = (float*)d_out;

  char* ws = (char*)d_ws;
  size_t off = 0;
  auto take = [&](size_t bytes)->char*{ char* p = ws + off; off = (off + bytes + 255) & ~(size_t)255; return p; };

  int*    src      = (int*)   take((size_t)Bb*Nn*Kk*4);
  float*  node     = (float*) take((size_t)Bb*Nn*Dd*4);
  bf16_t* node_bf  = (bf16_t*)take((size_t)Bb*Nn*Dd*2);
  bf16_t* agg_bf   = (bf16_t*)take((size_t)Bb*Nn*Dd*2);
  bf16_t* vproj_bf = (bf16_t*)take((size_t)Bb*Nn*256*2);
  bf16_t* hsrc_bf  = (bf16_t*)take((size_t)Bb*Nn*128*2);
  float*  hdst_f   = (float*) take((size_t)Bb*Nn*128*4);
  bf16_t* qw_bf    = (bf16_t*)take(((size_t)Bb*Nn*1024 + 2048)*2);  // +pad for B-frag overread
  bf16_t* Wt       = (bf16_t*)take((size_t)4*NCOLS*Dd*2);
  bf16_t* Wto      = (bf16_t*)take((size_t)3*Dd*Dd*2);
  bf16_t* WrbfT    = (bf16_t*)take((size_t)4*HIDh*NBnb*2);
  float*  t_hd     = (float*) take((size_t)4*Bb*HIDh*4);

  // weight prep
  wprep_kernel <<<dim3(4,512),  256, 0, stream>>>(Wv, Wk1, Wt);
  wprepM_kernel<<<dim3(4,1024), 256, 0, stream>>>(Wq, Wk2, Wt);
  wprepO_kernel<<<dim3(3,256),  256, 0, stream>>>(Wo, Wto);
  wprepR_kernel<<<dim3(4,128),  32,  0, stream>>>(Wk1, WrbfT);
  tprep_kernel <<<dim3(4,8),    128, 0, stream>>>(t, Wk1, bk1, t_hd);

  knn_kernel  <<<dim3(Bb*Nn/4), 256, 0, stream>>>(x, src);
  embed_kernel<<<dim3(Bb*Nn), 256, 0, stream>>>(y, t, We, node, node_bf);

  for (int l=0; l<4; l++){
    gemm_proj<<<dim3(64,24), 256, 0, stream>>>(node_bf, Wt, vproj_bf, hsrc_bf, hdst_f, qw_bf, l);
    attn_kernel<<<dim3(Bb*Nn), 256, 0, stream>>>(x, src, vproj_bf, hsrc_bf, hdst_f, qw_bf,
                                                 t_hd, WrbfT, Wv, Woo, agg_bf, out, l);
    if (l < 3){
      gemm_upd<<<dim3(64,4), 256, 0, stream>>>(agg_bf, Wto, node, node_bf, l);
    }
  }
}